// Round 1
// baseline (2641.750 us; speedup 1.0000x reference)
//
#include <hip/hip_runtime.h>

// Problem constants (reference: B=32, S=8192, D=32, C=256)
#define S_LEN 8192
#define BATCH 32
#define DH    32
#define NC    256

// sigmoid via native exp + rcp (1-2 ulp; threshold is ~2% relative -> huge margin)
__device__ __forceinline__ float sigf(float x) {
    return __builtin_amdgcn_rcpf(1.0f + __expf(-x));
}
__device__ __forceinline__ float rdlane(float v, int l) {
    return __int_as_float(__builtin_amdgcn_readlane(__float_as_int(v), l));
}
__device__ __forceinline__ float bperm(int byte_addr, float v) {
    return __int_as_float(__builtin_amdgcn_ds_bpermute(byte_addr, __float_as_int(v)));
}

// One wave per batch. Lane j owns gate columns k1=j (i-gate for j<32, f-gate for j>=32)
// and k2=j+64 (g-gate for j<32, o-gate for j>=32). h for column (j&31) is replicated
// in both half-waves so v_readlane(h, d) d=0..31 gives the full hidden state.
__global__ __launch_bounds__(64, 1) void lstm_scan_kernel(
    const float* __restrict__ x,      // (B,S)
    const float* __restrict__ bos,    // (D)
    const float* __restrict__ W_in,   // (1,D)
    const float* __restrict__ b_in,   // (D)
    const float* __restrict__ Wx,     // (D,4D)
    const float* __restrict__ Wh,     // (D,4D)
    const float* __restrict__ b_lstm, // (4D)
    float* __restrict__ hs)           // (B,S,D) workspace
{
    const int b    = blockIdx.x;
    const int lane = threadIdx.x;     // 0..63
    const int col  = lane & 31;
    const int k1   = lane;
    const int k2   = lane + 64;
    const bool lo  = lane < 32;

    // Recurrent weight columns live in VGPRs for the whole scan (64 regs).
    float wh1[DH], wh2[DH];
#pragma unroll
    for (int d = 0; d < DH; ++d) {
        wh1[d] = Wh[d * 4 * DH + k1];
        wh2[d] = Wh[d * 4 * DH + k2];
    }

    // Rank-1 input projection constants:
    //   zx[t,k] = x[t-1]*v_k + u_k   (t>=1),   zx[0,k] = z0_k
    float u1 = b_lstm[k1], u2 = b_lstm[k2];
    float z01 = u1, z02 = u2;         // bos @ Wx + b_lstm (bos is used raw, no W_in)
    float v1 = 0.f, v2 = 0.f;
#pragma unroll
    for (int d = 0; d < DH; ++d) {
        const float wx1 = Wx[d * 4 * DH + k1];
        const float wx2 = Wx[d * 4 * DH + k2];
        const float wi = W_in[d];
        v1 = fmaf(wi, wx1, v1);  v2 = fmaf(wi, wx2, v2);
        const float bi = b_in[d];
        u1 = fmaf(bi, wx1, u1);  u2 = fmaf(bi, wx2, u2);
        const float bd = bos[d];
        z01 = fmaf(bd, wx1, z01); z02 = fmaf(bd, wx2, z02);
    }

    // Branchless nonlinearity: s1 = sigmoid(z1) always (i or f gate);
    // s2 = tanh(z2) for lo lanes (g), sigmoid(z2) for hi lanes (o);
    // tanh(x) = 2*sigmoid(2x) - 1.
    const float m2 = lo ? 2.f : 1.f;
    const float aa = lo ? 2.f : 1.f;
    const float bb = lo ? -1.f : 0.f;
    const int swap_addr = (lane ^ 32) << 2;   // ds_bpermute byte address

    const float* xb  = x  + (size_t)b * S_LEN;
    float*       hsb = hs + (size_t)b * S_LEN * DH;

    float c = 0.f, h = 0.f;

    // Prefetch first x chunk: lane holds x[t-1] for t = chunk*64 + lane
    float xc;
    {
        const int xi = lane - 1;
        xc = (xi >= 0) ? xb[xi] : 0.f;
    }

    for (int chunk = 0; chunk < S_LEN / 64; ++chunk) {
        // Prefetch next chunk's x while this chunk computes (fully hidden).
        float xn = 0.f;
        if (chunk + 1 < S_LEN / 64) xn = xb[(chunk + 1) * 64 - 1 + lane];

        for (int i = 0; i < 64; ++i) {
            const float xs = rdlane(xc, i);
            // 8 partial accumulator chains -> issue-bound, not latency-bound.
            float p0 = fmaf(xs, v1, u1), p1 = 0.f, p2 = 0.f, p3 = 0.f;
            float q0 = fmaf(xs, v2, u2), q1 = 0.f, q2 = 0.f, q3 = 0.f;
#pragma unroll
            for (int d = 0; d < DH; d += 4) {
                const float h0 = rdlane(h, d);
                const float h1 = rdlane(h, d + 1);
                const float h2 = rdlane(h, d + 2);
                const float h3 = rdlane(h, d + 3);
                p0 = fmaf(h0, wh1[d],     p0);  q0 = fmaf(h0, wh2[d],     q0);
                p1 = fmaf(h1, wh1[d + 1], p1);  q1 = fmaf(h1, wh2[d + 1], q1);
                p2 = fmaf(h2, wh1[d + 2], p2);  q2 = fmaf(h2, wh2[d + 2], q2);
                p3 = fmaf(h3, wh1[d + 3], p3);  q3 = fmaf(h3, wh2[d + 3], q3);
            }
            float z1 = (p0 + p1) + (p2 + p3);
            float z2 = (q0 + q1) + (q2 + q3);
            if (chunk == 0 && i == 0) { z1 = z01; z2 = z02; }  // uniform select

            const float s1 = sigf(z1);
            const float s2 = fmaf(aa, sigf(m2 * z2), bb);

            // Exchange with partner lane (j ^ 32): hi half holds (f, o) / lo holds (i, g)
            const float s1p = bperm(swap_addr, s1);
            const float s2p = bperm(swap_addr, s2);

            const float f_ = lo ? s1p : s1;
            const float ig = lo ? s1 * s2 : s1p * s2p;   // sig(i)*tanh(g)
            const float o_ = lo ? s2p : s2;

            c = fmaf(f_, c, ig);
            const float tc = fmaf(2.f, sigf(2.f * c), -1.f);  // tanh(c)
            h = o_ * tc;

            if (lo) hsb[(size_t)(chunk * 64 + i) * DH + col] = h;
        }
        xc = xn;
    }
}

// Projection: logits[b,t,c] = hs[b,t,:] @ W_out[:,c] + b_out[c]
// Block = 256 threads, one output column per thread, 128 t-rows per block.
// W_out column in VGPRs; h rows staged in LDS (broadcast reads); coalesced stores.
__global__ __launch_bounds__(256, 4) void proj_kernel(
    const float* __restrict__ hs,     // (B,S,D)
    const float* __restrict__ W_out,  // (D,C)
    const float* __restrict__ b_out,  // (C)
    float* __restrict__ out)          // (B,S,C)
{
    __shared__ float hbuf[128 * DH];  // 16 KiB
    const int tid = threadIdx.x;
    const int b   = blockIdx.y;
    const int t0  = blockIdx.x * 128;

    // Stage 128 rows of h (coalesced float4 copy)
    const float4* src4 = (const float4*)(hs + ((size_t)b * S_LEN + t0) * DH);
    float4* dst4 = (float4*)hbuf;
#pragma unroll
    for (int k = 0; k < 4; ++k) dst4[tid + k * 256] = src4[tid + k * 256];
    __syncthreads();

    const int cc = tid;               // output column
    float w[DH];
#pragma unroll
    for (int d = 0; d < DH; ++d) w[d] = W_out[d * NC + cc];
    const float bo = b_out[cc];

    float* dst = out + ((size_t)b * S_LEN + t0) * NC + cc;
    for (int r = 0; r < 128; ++r) {
        float acc = bo;
#pragma unroll
        for (int d = 0; d < DH; ++d) acc = fmaf(hbuf[r * DH + d], w[d], acc);
        dst[(size_t)r * NC] = acc;    // 64 consecutive lanes -> 256B coalesced
    }
}

extern "C" void kernel_launch(void* const* d_in, const int* in_sizes, int n_in,
                              void* d_out, int out_size, void* d_ws, size_t ws_size,
                              hipStream_t stream) {
    const float* x      = (const float*)d_in[0];
    const float* bos    = (const float*)d_in[1];
    const float* W_in   = (const float*)d_in[2];
    const float* b_in   = (const float*)d_in[3];
    const float* Wx     = (const float*)d_in[4];
    const float* Wh     = (const float*)d_in[5];
    const float* b_lstm = (const float*)d_in[6];
    const float* W_out  = (const float*)d_in[7];
    const float* b_out  = (const float*)d_in[8];

    float* out = (float*)d_out;
    float* hs  = (float*)d_ws;   // needs B*S*D*4 = 33.5 MB of workspace

    lstm_scan_kernel<<<dim3(BATCH), dim3(64), 0, stream>>>(
        x, bos, W_in, b_in, Wx, Wh, b_lstm, hs);
    proj_kernel<<<dim3(S_LEN / 128, BATCH), dim3(256), 0, stream>>>(
        hs, W_out, b_out, out);
}